// Round 4
// baseline (281.671 us; speedup 1.0000x reference)
//
#include <hip/hip_runtime.h>

// ---------------------------------------------------------------------------
// Fused GQA attention: B=2, L=2048, D=1024, H=16, G=2, HPG=8, DQK=DV=128.
// Inputs fp32, OUTPUT fp32. bf16 MFMA compute, fp32 accumulation.
//
// Attention core on 32x32x16 MFMA with fully in-register P via
// v_cvt_pk_bf16_f32 + v_permlane32_swap_b32 (T12).
//   32x32x16 layouts: A[m=lane&31][k=(lane>>5)*8+j], B[k=(lane>>5)*8+j][n=lane&31],
//   C/D: col=lane&31, row=(reg&3)+8*(reg>>2)+4*(lane>>5).
// 4 waves = 2 q-subtiles(32 rows) x 2 kv-halves(32 keys); KVBLK=64.
//
// ROUND-3: occupancy play. attn was 46% dual-pipe-idle at 2 blocks/CU
// (LDS 64KB, grid 512 = exactly 2/CU). Now: K single-buffered (read only in
// the QK phase; restaged after a mid-iter barrier), V double-buffered ->
// LDS 48KB -> 3 blocks/CU; grid unpaired 1024 blocks (qt = 31-bx, longest
// first) -> 12 waves/CU. s_setprio(1) around MFMA clusters (T5).
// Accumulators stay NAMED registers (rule #20 - round-2 lesson).
// ---------------------------------------------------------------------------

typedef __bf16 bf16;
typedef __bf16 bf16x8 __attribute__((ext_vector_type(8)));
typedef __bf16 bf16x4 __attribute__((ext_vector_type(4)));
typedef float f32x4 __attribute__((ext_vector_type(4)));
typedef float f32x16 __attribute__((ext_vector_type(16)));
typedef float float4v __attribute__((ext_vector_type(4)));

#define MFMA_BF16(a, b, c) __builtin_amdgcn_mfma_f32_16x16x32_bf16((a), (b), (c), 0, 0, 0)
#define MFMA32(a, b, c)    __builtin_amdgcn_mfma_f32_32x32x16_bf16((a), (b), (c), 0, 0, 0)

static constexpr int Bz = 2, Lz = 2048, Dz = 1024;
static constexpr int Hz = 16, Gz = 2;
static constexpr int DQKz = 128, DVz = 128;

__device__ __forceinline__ void async_copy16(const bf16* g, bf16* l) {
    __builtin_amdgcn_global_load_lds(
        (const __attribute__((address_space(1))) unsigned int*)g,
        (__attribute__((address_space(3))) unsigned int*)l, 16, 0, 0);
}

__device__ __forceinline__ unsigned cvt_pk_bf16(float lo, float hi) {
    unsigned r;
    asm("v_cvt_pk_bf16_f32 %0, %1, %2" : "=v"(r) : "v"(lo), "v"(hi));
    return r;
}

// ---------------- prep: cvt q/k/v + all 4 weight transposes, one launch -----
// grid: 10752 blocks x 256 thr.
//   [0,6144): fp32->bf16 cvt of in_q/in_k/in_v (2048 blocks each, 2048 el/blk)
//   [6144,10752): 32x32 transpose tiles: Wq 2048, Wk 256, Wv 256, Wo 2048
__global__ __launch_bounds__(256) void prep(
    const float* __restrict__ q, const float* __restrict__ k,
    const float* __restrict__ v, bf16* __restrict__ dq,
    bf16* __restrict__ dk, bf16* __restrict__ dv,
    const float* __restrict__ Wq, const float* __restrict__ Wk,
    const float* __restrict__ Wv, const float* __restrict__ Wo,
    bf16* __restrict__ WqT, bf16* __restrict__ WkT,
    bf16* __restrict__ WvT, bf16* __restrict__ WoT)
{
    int bid = blockIdx.x;
    if (bid < 6144) {
        const float* s = bid < 2048 ? q : (bid < 4096 ? k : v);
        bf16* d = bid < 2048 ? dq : (bid < 4096 ? dk : dv);
        int i = (bid & 2047) * 2048 + threadIdx.x * 8;
        float4v a = *(const float4v*)(s + i);
        float4v b = *(const float4v*)(s + i + 4);
        bf16x8 o;
        #pragma unroll
        for (int j = 0; j < 4; ++j) { o[j] = (bf16)a[j]; o[j + 4] = (bf16)b[j]; }
        *(bf16x8*)(d + i) = o;
        return;
    }
    bid -= 6144;
    const float* W; bf16* WT; int K, N;
    if (bid < 2048)      { W = Wq; WT = WqT; K = 1024; N = 2048; }
    else if (bid < 2304) { W = Wk; WT = WkT; K = 1024; N = 256;  bid -= 2048; }
    else if (bid < 2560) { W = Wv; WT = WvT; K = 1024; N = 256;  bid -= 2304; }
    else                 { W = Wo; WT = WoT; K = 2048; N = 1024; bid -= 2560; }
    int tiles_n = N >> 5;
    int n0 = (bid % tiles_n) * 32, k0 = (bid / tiles_n) * 32;

    __shared__ bf16 t[32][33];
    int tx = threadIdx.x & 31, ty = threadIdx.x >> 5;
    #pragma unroll
    for (int i = 0; i < 4; ++i)
        t[ty + i * 8][tx] = (bf16)W[(size_t)(k0 + ty + i * 8) * N + n0 + tx];
    __syncthreads();
    #pragma unroll
    for (int i = 0; i < 4; ++i)
        WT[(size_t)(n0 + ty + i * 8) * K + k0 + tx] = t[tx][ty + i * 8];
}

// ---------------- pipelined GEMM body: 128x128 tile, BK64, 512 thr ----------
// 8 waves as 2(m) x 4(n); wave-tile 64x32. Double-buffered LDS, single
// barrier per k-iter, prefetch issued right after the barrier (attn-proven).
template <typename TC>
__device__ __forceinline__ void gemm_tile(
    const bf16* __restrict__ A, const bf16* __restrict__ BT,
    const float* __restrict__ bias, float scale, TC* __restrict__ C,
    int M, int N, int K, int m0, int n0, bool trans_out,
    bf16 (&As)[2][128 * 64], bf16 (&Bs)[2][128 * 64])
{
    const int tid  = threadIdx.x;        // 512
    const int wave = tid >> 6;
    const int lane = tid & 63;
    const int quad = lane >> 4;
    const int l16  = lane & 15;
    const int sw   = l16 & 7;
    const int wm = wave >> 2, wn = wave & 3;

    f32x4 acc[4][2] = {};

    auto stage = [&](int k0, int buf) {
        #pragma unroll
        for (int s = 0; s < 2; ++s) {
            int i = s * 512 + tid;
            int row = i >> 3, c = (i & 7) ^ (row & 7);
            async_copy16(A + (size_t)(m0 + row) * K + k0 + c * 8, &As[buf][i * 8]);
        }
        #pragma unroll
        for (int s = 0; s < 2; ++s) {
            int i = s * 512 + tid;
            int row = i >> 3, c = (i & 7) ^ (row & 7);
            async_copy16(BT + (size_t)(n0 + row) * K + k0 + c * 8, &Bs[buf][i * 8]);
        }
    };

    stage(0, 0);
    int cur = 0;
    for (int k0 = 0; k0 < K; k0 += 64) {
        __syncthreads();                    // drains loads issued last iter
        if (k0 + 64 < K) stage(k0 + 64, cur ^ 1);

        #pragma unroll
        for (int ks = 0; ks < 2; ++ks) {
            bf16x8 af[4], bfv[2];
            #pragma unroll
            for (int mt = 0; mt < 4; ++mt)
                af[mt] = *(const bf16x8*)(&As[cur][((wm * 64 + mt * 16 + l16) * 8
                                                    + ((ks * 4 + quad) ^ sw)) * 8]);
            #pragma unroll
            for (int nt = 0; nt < 2; ++nt)
                bfv[nt] = *(const bf16x8*)(&Bs[cur][((wn * 32 + nt * 16 + l16) * 8
                                                     + ((ks * 4 + quad) ^ sw)) * 8]);
            #pragma unroll
            for (int mt = 0; mt < 4; ++mt)
                #pragma unroll
                for (int nt = 0; nt < 2; ++nt)
                    acc[mt][nt] = MFMA_BF16(af[mt], bfv[nt], acc[mt][nt]);
        }
        cur ^= 1;
    }

    #pragma unroll
    for (int nt = 0; nt < 2; ++nt) {
        int col = n0 + wn * 32 + nt * 16 + l16;
        float bv = bias[col];
        #pragma unroll
        for (int mt = 0; mt < 4; ++mt) {
            int row = m0 + wm * 64 + mt * 16 + quad * 4;
            if (trans_out) {
                struct V4 { TC v[4]; } o;
                #pragma unroll
                for (int r = 0; r < 4; ++r)
                    o.v[r] = (TC)((acc[mt][nt][r] + bv) * scale);
                *(V4*)(&C[(size_t)col * M + row]) = o;
            } else {
                #pragma unroll
                for (int r = 0; r < 4; ++r)
                    C[(size_t)(row + r) * N + col] =
                        (TC)((acc[mt][nt][r] + bv) * scale);
            }
        }
    }
}

// ---------------- Q+K+V projections in one launch ---------------------------
// grid 640: [0,512) Q-proj (N=2048); [512,576) K-proj; [576,640) V-proj
// (transposed output VwT[dv][token]). All K=1024.
__global__ __launch_bounds__(512, 4) void proj_qkv(
    const bf16* __restrict__ aq, const bf16* __restrict__ ak,
    const bf16* __restrict__ av, const bf16* __restrict__ WqT,
    const bf16* __restrict__ WkT, const bf16* __restrict__ WvT,
    const float* __restrict__ bq, const float* __restrict__ bk,
    const float* __restrict__ bv, const float* __restrict__ qsc,
    bf16* __restrict__ Qw, bf16* __restrict__ Kw, bf16* __restrict__ VwT)
{
    __shared__ bf16 As[2][128 * 64];
    __shared__ bf16 Bs[2][128 * 64];
    int bid = blockIdx.x;
    if (bid < 512) {
        // scale = qsc / sqrt(128) * log2(e)  (exp2-domain softmax)
        float scale = qsc[0] * 0.08838834764831845f * 1.4426950408889634f;
        gemm_tile<bf16>(aq, WqT, bq, scale, Qw, 4096, 2048, 1024,
                        (bid >> 4) * 128, (bid & 15) * 128, false, As, Bs);
    } else if (bid < 576) {
        int b2 = bid - 512;
        gemm_tile<bf16>(ak, WkT, bk, 1.0f, Kw, 4096, 256, 1024,
                        (b2 >> 1) * 128, (b2 & 1) * 128, false, As, Bs);
    } else {
        int b2 = bid - 576;
        gemm_tile<bf16>(av, WvT, bv, 1.0f, VwT, 4096, 256, 1024,
                        (b2 >> 1) * 128, (b2 & 1) * 128, true, As, Bs);
    }
}

// ---------------- output projection -----------------------------------------
__global__ __launch_bounds__(512, 4) void proj_o(
    const bf16* __restrict__ Cw, const bf16* __restrict__ WoT,
    const float* __restrict__ bo, float* __restrict__ out)
{
    __shared__ bf16 As[2][128 * 64];
    __shared__ bf16 Bs[2][128 * 64];
    gemm_tile<float>(Cw, WoT, bo, 1.0f, out, 4096, 1024, 2048,
                     (blockIdx.x >> 3) * 128, (blockIdx.x & 7) * 128,
                     false, As, Bs);
}

// ---------------- flash attention (causal, GQA), 32x32 MFMA, in-reg P -------
// grid (32,16,2); 256 thr = 4 waves = 2 q-subtiles(32 rows) x 2 kv-halves
// (32 keys). Block tile: 64 q-rows x 64 keys per kt; qt = 31 - bx (longest
// blocks dispatch first). LDS 48 KB: K single-buffered (16 KB, read only in
// the QK phase, restaged after mid-iter barrier), V double-buffered (32 KB)
// -> 3 blocks/CU. Per iter:
//   [A: syncthreads (drains stage loads)] QK(Kb) [B: syncthreads]
//   stage K(t+1)->Kb, V(t+1)->Vb[cur^1]   (loads land during softmax+PV)
//   softmax (in-reg P via cvt_pk+permlane32_swap) ; PV(Vb[cur])
// kv-half partials combined once per block in LDS. Accumulators NAMED regs.
__global__ __launch_bounds__(256, 3) void attn_fused(
    const bf16* __restrict__ Q,    // [B*L, H*128], pre-scaled
    const bf16* __restrict__ Kp,   // [B*L, G*128]
    const bf16* __restrict__ VT,   // [G*128, B*L]
    bf16* __restrict__ ctx)        // [B*L, H*128]
{
    // flat 48 KB: Kb [0,8192), Vb0 [8192,16384), Vb1 [16384,24576)  (bf16)
    __shared__ bf16 smem[24576];

    const int tid  = threadIdx.x;
    const int wave = tid >> 6;
    const int lane = tid & 63;
    const int hi   = lane >> 5;
    const int l31  = lane & 31;
    const int s7   = l31 & 7;
    const int wq   = wave >> 1;    // q sub-tile (rows wq*32..+32 of block tile)
    const int kvw  = wave & 1;     // kv half (keys kvw*32..+32 of each kt tile)

    const int h = blockIdx.y;
    const int b = blockIdx.z;
    const int g = h >> 3;

    const bf16* kgbase = Kp + (size_t)(b * Lz) * (Gz * DQKz) + g * DQKz;
    const bf16* vgbase = VT + (size_t)(g * DVz) * (Bz * Lz) + b * Lz;

    // staging offsets (kt-invariant). LDS chunk ch of row r holds global
    // chunk ch^(r&7) (involution; read side applies the same XOR).
    int kgo[4], vgo[4], ldso[4];
    #pragma unroll
    for (int s = 0; s < 4; ++s) {
        int i = s * 256 + tid;
        ldso[s] = i * 8;
        int key = i >> 4, ck = (i & 15) ^ (key & 7);
        kgo[s] = key * (Gz * DQKz) + ck * 8;
        int dvr = i >> 3, cv = (i & 7) ^ (dvr & 7);
        vgo[s] = dvr * (Bz * Lz) + cv * 8;
    }
    auto stage_K = [&](int kt) {
        const bf16* kb = kgbase + (size_t)(kt * 64) * (Gz * DQKz);
        #pragma unroll
        for (int s = 0; s < 4; ++s) async_copy16(kb + kgo[s], smem + ldso[s]);
    };
    auto stage_V = [&](int kt, int buf) {
        const bf16* vb = vgbase + kt * 64;
        #pragma unroll
        for (int s = 0; s < 4; ++s)
            async_copy16(vb + vgo[s], smem + 8192 + buf * 8192 + ldso[s]);
    };

    // LDS read offsets (kt-invariant). K A-frag: row=kvw*32+l31, d-chunk
    // 2ks+hi; V A-frag: row=dt*32+l31, key-chunk kvw*4+kss*2+hi.
    int koff[8];
    #pragma unroll
    for (int ks = 0; ks < 8; ++ks)
        koff[ks] = ((kvw * 32 + l31) * 16 + ((ks * 2 + hi) ^ s7)) * 8;
    int voff[4][2];
    #pragma unroll
    for (int dt = 0; dt < 4; ++dt)
        #pragma unroll
        for (int kss = 0; kss < 2; ++kss)
            voff[dt][kss] = ((dt * 32 + l31) * 8
                             + ((kvw * 4 + kss * 2 + hi) ^ s7)) * 8;

    const int qt  = 31 - (int)blockIdx.x;   // longest blocks first
    const int q0  = qt * 64;
    const int nkt = qt + 1;
    const int qrow = q0 + wq * 32 + l31;

    // Q fragments in registers: B-operand, qrow = lane col, 8 k-steps
    bf16x8 qf[8];
    {
        const bf16* qbase = Q + (size_t)(b * Lz + qrow) * (Hz * DQKz) + h * DQKz;
        #pragma unroll
        for (int s = 0; s < 8; ++s)
            qf[s] = *(const bf16x8*)(qbase + s * 16 + hi * 8);
    }

    // O^T dv-tiles: dv = dt*32 + crow, col = qrow. NAMED regs (rule #20).
    f32x16 oacc0 = {}, oacc1 = {}, oacc2 = {}, oacc3 = {};
    float lsum = 0.0f;

    stage_K(0);
    stage_V(0, 0);
    int cur = 0;

    for (int kt = 0; kt < nkt; ++kt) {
        __syncthreads();          // A: drains stage loads issued last iter

        const bf16* vcur = smem + 8192 + cur * 8192;

        // S^T[key = kvw*32 + crow][qrow = l31], K-dim 128 = 8 steps
        f32x16 sacc = {};
        __builtin_amdgcn_s_setprio(1);
        #pragma unroll
        for (int ks = 0; ks < 8; ++ks) {
            bf16x8 kf = *(const bf16x8*)(smem + koff[ks]);
            sacc = MFMA32(kf, qf[ks], sacc);
        }
        __builtin_amdgcn_s_setprio(0);

        __syncthreads();          // B: all waves done reading Kb
        if (kt + 1 < nkt) {       // restage K + next V; lands during SM+PV
            stage_K(kt + 1);
            stage_V(kt + 1, cur ^ 1);
        }

        // P = exp2(S - 8); mask only the diagonal tile.
        float pv[16];
        if (kt == nkt - 1) {
            #pragma unroll
            for (int r = 0; r < 16; ++r) {
                int key = kvw * 32 + (r & 3) + 8 * (r >> 2) + 4 * hi;
                pv[r] = (key > wq * 32 + l31) ? 0.0f
                                              : exp2f(sacc[r] - 8.0f);
            }
        } else {
            #pragma unroll
            for (int r = 0; r < 16; ++r)
                pv[r] = exp2f(sacc[r] - 8.0f);
        }
        lsum += ((pv[0] + pv[1]) + (pv[2] + pv[3]))
              + ((pv[4] + pv[5]) + (pv[6] + pv[7]))
              + ((pv[8] + pv[9]) + (pv[10] + pv[11]))
              + ((pv[12] + pv[13]) + (pv[14] + pv[15]));

        // P -> PV B-operand in registers (T12): pack pairs, swap halves.
        // After swap(c0,c2): c0 = rows{0,1}/{8,9}, c2 = rows{4,5}/{12,13}.
        unsigned c0 = cvt_pk_bf16(pv[0],  pv[1]);
        unsigned c1 = cvt_pk_bf16(pv[2],  pv[3]);
        unsigned c2 = cvt_pk_bf16(pv[4],  pv[5]);
        unsigned c3 = cvt_pk_bf16(pv[6],  pv[7]);
        unsigned c4 = cvt_pk_bf16(pv[8],  pv[9]);
        unsigned c5 = cvt_pk_bf16(pv[10], pv[11]);
        unsigned c6 = cvt_pk_bf16(pv[12], pv[13]);
        unsigned c7 = cvt_pk_bf16(pv[14], pv[15]);
        asm("v_permlane32_swap_b32 %0, %1" : "+v"(c0), "+v"(c2));
        asm("v_permlane32_swap_b32 %0, %1" : "+v"(c1), "+v"(c3));
        asm("v_permlane32_swap_b32 %0, %1" : "+v"(c4), "+v"(c6));
        asm("v_permlane32_swap_b32 %0, %1" : "+v"(c5), "+v"(c7));
        union { unsigned u[4]; bf16x8 v; } p0 = {{c0, c1, c2, c3}};
        union { unsigned u[4]; bf16x8 v; } p1 = {{c4, c5, c6, c7}};

        // O^T += V^T P^T : 4 dv-tiles x 2 k-steps (wave's 32 keys)
        __builtin_amdgcn_s_setprio(1);
        {
            bf16x8 vf;
            vf = *(const bf16x8*)(vcur + voff[0][0]); oacc0 = MFMA32(vf, p0.v, oacc0);
            vf = *(const bf16x8*)(vcur + voff[0][1]); oacc0 = MFMA32(vf, p1.v, oacc0);
            vf = *(const bf16x8*)(vcur + voff[1][0]); oacc1 = MFMA32(vf, p0.v, oacc1);
            vf = *(const bf16x8*)(vcur + voff[1][1]); oacc1 = MFMA32(vf, p1.v, oacc1);
            vf = *(const bf16x8*)(vcur + voff[2][0]); oacc2 = MFMA32(vf, p0.v, oacc2);
            vf = *(const bf16x8*)(vcur + voff[2][1]); oacc2 = MFMA32(vf, p1.v, oacc2);
            vf = *(const bf16x8*)(vcur + voff[3][0]); oacc3 = MFMA32(vf, p0.v, oacc3);
            vf = *(const bf16x8*)(vcur + voff[3][1]); oacc3 = MFMA32(vf, p1.v, oacc3);
        }
        __builtin_amdgcn_s_setprio(0);
        cur ^= 1;
    }

    // in-wave: combine hi halves (same qrow)
    lsum += __shfl_xor(lsum, 32);

    // cross-wave (kv-half) combine via LDS; stride 20 = conflict-free.
    // Flat over smem: E0 [0,5120), E1 [5120,10240), LS [10240,10368) floats.
    float* SM = (float*)smem;
    float* E0 = SM;
    float* E1 = SM + 5120;
    float* LS = SM + 10240;
    __syncthreads();                   // all waves done with K/V tiles

    // write the tiles we DON'T keep (partner's half) - static indices.
    auto store_partial = [&](f32x16 v, float* E) {
        #pragma unroll
        for (int j = 0; j < 4; ++j) {
            f32x4 v4 = { v[4 * j], v[4 * j + 1], v[4 * j + 2], v[4 * j + 3] };
            *(f32x4*)&E[(wave * 64 + lane) * 20 + 4 * j] = v4;
        }
    };
    if (kvw == 0) { store_partial(oacc2, E0); store_partial(oacc3, E1); }
    else          { store_partial(oacc0, E0); store_partial(oacc1, E1); }
    if (lane < 32) LS[wave * 32 + lane] = lsum;
    __syncthreads();
    lsum += LS[(wave ^ 1) * 32 + l31];
    const float inv = 1.0f / lsum;

    // finalize kept tiles: own partial + partner's, normalize, store.
    bf16* cbase = ctx + (size_t)(b * Lz + qrow) * (Hz * DVz) + h * DVz;
    auto finalize = [&](f32x16 v, float* E, int dt) {
        #pragma unroll
        for (int j = 0; j < 4; ++j) {
            f32x4 p4 = *(const f32x4*)&E[((wave ^ 1) * 64 + lane) * 20 + 4 * j];
            bf16x4 o4;
            #pragma unroll
            for (int r = 0; r < 4; ++r)
                o4[r] = (bf16)((v[4 * j + r] + p4[r]) * inv);
            *(bf16x4*)&cbase[dt * 32 + j * 8 + hi * 4] = o4;
        }
    };
    if (kvw == 0) { finalize(oacc0, E0, 0); finalize(oacc1, E1, 1); }
    else          { finalize(oacc2, E0, 2); finalize(oacc3, E1, 3); }
}

// ---------------------------------------------------------------------------
extern "C" void kernel_launch(void* const* d_in, const int* in_sizes, int n_in,
                              void* d_out, int out_size, void* d_ws, size_t ws_size,
                              hipStream_t stream)
{
    (void)in_sizes; (void)n_in; (void)out_size; (void)ws_size;

    const float* in_q = (const float*)d_in[0];
    const float* in_k = (const float*)d_in[1];
    const float* in_v = (const float*)d_in[2];
    const float* Wq   = (const float*)d_in[3];
    const float* bq   = (const float*)d_in[4];
    const float* Wk   = (const float*)d_in[5];
    const float* bk   = (const float*)d_in[6];
    const float* Wv   = (const float*)d_in[7];
    const float* bv   = (const float*)d_in[8];
    const float* Wo   = (const float*)d_in[9];
    const float* bo   = (const float*)d_in[10];
    const float* qsc  = (const float*)d_in[11];
    float* out = (float*)d_out;

    const int M = Bz * Lz;                       // 4096
    const int NQ = Hz * DQKz;                    // 2048
    const int NKV = Gz * DQKz;                   // 256

    // workspace (bf16 elems), ~53 MB; ak/av alias Cw (consumed before attn
    // writes ctx there).
    bf16* aq  = (bf16*)d_ws;                     // 4M
    bf16* WqT = aq  + (size_t)M * Dz;            // 2M
    bf16* WkT = WqT + (size_t)NQ * Dz;           // 0.25M
    bf16* WvT = WkT + (size_t)NKV * Dz;          // 0.25M
    bf16* WoT = WvT + (size_t)NKV * Dz;          // 2M
    bf16* Qw  = WoT + (size_t)Dz * NQ;           // 8M
    bf16* Kw  = Qw  + (size_t)M * NQ;            // 1M
    bf16* VwT = Kw  + (size_t)M * NKV;           // 1M
    bf16* Cw  = VwT + (size_t)NKV * M;           // 8M
    bf16* ak  = Cw;                              // alias (4M)
    bf16* av  = Cw + (size_t)M * Dz;             // alias (4M)

    // 1) prep: cvt + weight transposes
    prep<<<dim3(10752), dim3(256), 0, stream>>>(
        in_q, in_k, in_v, aq, ak, av, Wq, Wk, Wv, Wo, WqT, WkT, WvT, WoT);

    // 2) Q/K/V projections (one launch, 640 blocks)
    proj_qkv<<<dim3(640), dim3(512), 0, stream>>>(
        aq, ak, av, WqT, WkT, WvT, bq, bk, bv, qsc, Qw, Kw, VwT);

    // 3) attention (unpaired grid, longest-first; 3 blocks/CU)
    attn_fused<<<dim3(32, Hz, Bz), dim3(256), 0, stream>>>(Qw, Kw, VwT, Cw);

    // 4) output projection -> fp32 out
    proj_o<<<dim3(256), dim3(512), 0, stream>>>(Cw, WoT, bo, out);
}

// Round 5
// 248.298 us; speedup vs baseline: 1.1344x; 1.1344x over previous
//
#include <hip/hip_runtime.h>

// ---------------------------------------------------------------------------
// Fused GQA attention: B=2, L=2048, D=1024, H=16, G=2, HPG=8, DQK=DV=128.
// Inputs fp32, OUTPUT fp32. bf16 MFMA compute, fp32 accumulation.
//
// Attention core on 32x32x16 MFMA with fully in-register P via
// v_cvt_pk_bf16_f32 + v_permlane32_swap_b32 (T12).
//   32x32x16 layouts: A[m=lane&31][k=(lane>>5)*8+j], B[k=(lane>>5)*8+j][n=lane&31],
//   C/D: col=lane&31, row=(reg&3)+8*(reg>>2)+4*(lane>>5).
// 4 waves = 2 q-subtiles(32 rows) x 2 kv-halves(32 keys); KVBLK=64.
//
// ROUND-4 LESSON: unpaired LPT grid (1024 var-length blocks) COLLAPSED
// occupancy (13.9%): longest blocks all start together, nothing backfills.
// Reverted to the balanced 2-pass paired grid (every block = 33 iters).
//
// ROUND-5: T15 software pipeline, ONE barrier/iter. K staged one tile ahead
// of V; iter t: stage K(t+2)/V(t+1); QK(t+1) -> sacc_next (independent MFMA
// chain) overlaps SM(t) (VALU) on sacc_cur; then PV(t). Two NAMED S
// accumulators rotated by unroll-2 (rule #20). setprio around PV only.
// ---------------------------------------------------------------------------

typedef __bf16 bf16;
typedef __bf16 bf16x8 __attribute__((ext_vector_type(8)));
typedef __bf16 bf16x4 __attribute__((ext_vector_type(4)));
typedef float f32x4 __attribute__((ext_vector_type(4)));
typedef float f32x16 __attribute__((ext_vector_type(16)));
typedef float float4v __attribute__((ext_vector_type(4)));

#define MFMA_BF16(a, b, c) __builtin_amdgcn_mfma_f32_16x16x32_bf16((a), (b), (c), 0, 0, 0)
#define MFMA32(a, b, c)    __builtin_amdgcn_mfma_f32_32x32x16_bf16((a), (b), (c), 0, 0, 0)

static constexpr int Bz = 2, Lz = 2048, Dz = 1024;
static constexpr int Hz = 16, Gz = 2;
static constexpr int DQKz = 128, DVz = 128;

__device__ __forceinline__ void async_copy16(const bf16* g, bf16* l) {
    __builtin_amdgcn_global_load_lds(
        (const __attribute__((address_space(1))) unsigned int*)g,
        (__attribute__((address_space(3))) unsigned int*)l, 16, 0, 0);
}

__device__ __forceinline__ unsigned cvt_pk_bf16(float lo, float hi) {
    unsigned r;
    asm("v_cvt_pk_bf16_f32 %0, %1, %2" : "=v"(r) : "v"(lo), "v"(hi));
    return r;
}

// ---------------- prep: cvt q/k/v + all 4 weight transposes, one launch -----
// grid: 10752 blocks x 256 thr.
//   [0,6144): fp32->bf16 cvt of in_q/in_k/in_v (2048 blocks each, 2048 el/blk)
//   [6144,10752): 32x32 transpose tiles: Wq 2048, Wk 256, Wv 256, Wo 2048
__global__ __launch_bounds__(256) void prep(
    const float* __restrict__ q, const float* __restrict__ k,
    const float* __restrict__ v, bf16* __restrict__ dq,
    bf16* __restrict__ dk, bf16* __restrict__ dv,
    const float* __restrict__ Wq, const float* __restrict__ Wk,
    const float* __restrict__ Wv, const float* __restrict__ Wo,
    bf16* __restrict__ WqT, bf16* __restrict__ WkT,
    bf16* __restrict__ WvT, bf16* __restrict__ WoT)
{
    int bid = blockIdx.x;
    if (bid < 6144) {
        const float* s = bid < 2048 ? q : (bid < 4096 ? k : v);
        bf16* d = bid < 2048 ? dq : (bid < 4096 ? dk : dv);
        int i = (bid & 2047) * 2048 + threadIdx.x * 8;
        float4v a = *(const float4v*)(s + i);
        float4v b = *(const float4v*)(s + i + 4);
        bf16x8 o;
        #pragma unroll
        for (int j = 0; j < 4; ++j) { o[j] = (bf16)a[j]; o[j + 4] = (bf16)b[j]; }
        *(bf16x8*)(d + i) = o;
        return;
    }
    bid -= 6144;
    const float* W; bf16* WT; int K, N;
    if (bid < 2048)      { W = Wq; WT = WqT; K = 1024; N = 2048; }
    else if (bid < 2304) { W = Wk; WT = WkT; K = 1024; N = 256;  bid -= 2048; }
    else if (bid < 2560) { W = Wv; WT = WvT; K = 1024; N = 256;  bid -= 2304; }
    else                 { W = Wo; WT = WoT; K = 2048; N = 1024; bid -= 2560; }
    int tiles_n = N >> 5;
    int n0 = (bid % tiles_n) * 32, k0 = (bid / tiles_n) * 32;

    __shared__ bf16 t[32][33];
    int tx = threadIdx.x & 31, ty = threadIdx.x >> 5;
    #pragma unroll
    for (int i = 0; i < 4; ++i)
        t[ty + i * 8][tx] = (bf16)W[(size_t)(k0 + ty + i * 8) * N + n0 + tx];
    __syncthreads();
    #pragma unroll
    for (int i = 0; i < 4; ++i)
        WT[(size_t)(n0 + ty + i * 8) * K + k0 + tx] = t[tx][ty + i * 8];
}

// ---------------- pipelined GEMM body: 128x128 tile, BK64, 512 thr ----------
// 8 waves as 2(m) x 4(n); wave-tile 64x32. Double-buffered LDS, single
// barrier per k-iter, prefetch issued right after the barrier (attn-proven).
template <typename TC>
__device__ __forceinline__ void gemm_tile(
    const bf16* __restrict__ A, const bf16* __restrict__ BT,
    const float* __restrict__ bias, float scale, TC* __restrict__ C,
    int M, int N, int K, int m0, int n0, bool trans_out,
    bf16 (&As)[2][128 * 64], bf16 (&Bs)[2][128 * 64])
{
    const int tid  = threadIdx.x;        // 512
    const int wave = tid >> 6;
    const int lane = tid & 63;
    const int quad = lane >> 4;
    const int l16  = lane & 15;
    const int sw   = l16 & 7;
    const int wm = wave >> 2, wn = wave & 3;

    f32x4 acc[4][2] = {};

    auto stage = [&](int k0, int buf) {
        #pragma unroll
        for (int s = 0; s < 2; ++s) {
            int i = s * 512 + tid;
            int row = i >> 3, c = (i & 7) ^ (row & 7);
            async_copy16(A + (size_t)(m0 + row) * K + k0 + c * 8, &As[buf][i * 8]);
        }
        #pragma unroll
        for (int s = 0; s < 2; ++s) {
            int i = s * 512 + tid;
            int row = i >> 3, c = (i & 7) ^ (row & 7);
            async_copy16(BT + (size_t)(n0 + row) * K + k0 + c * 8, &Bs[buf][i * 8]);
        }
    };

    stage(0, 0);
    int cur = 0;
    for (int k0 = 0; k0 < K; k0 += 64) {
        __syncthreads();                    // drains loads issued last iter
        if (k0 + 64 < K) stage(k0 + 64, cur ^ 1);

        #pragma unroll
        for (int ks = 0; ks < 2; ++ks) {
            bf16x8 af[4], bfv[2];
            #pragma unroll
            for (int mt = 0; mt < 4; ++mt)
                af[mt] = *(const bf16x8*)(&As[cur][((wm * 64 + mt * 16 + l16) * 8
                                                    + ((ks * 4 + quad) ^ sw)) * 8]);
            #pragma unroll
            for (int nt = 0; nt < 2; ++nt)
                bfv[nt] = *(const bf16x8*)(&Bs[cur][((wn * 32 + nt * 16 + l16) * 8
                                                     + ((ks * 4 + quad) ^ sw)) * 8]);
            #pragma unroll
            for (int mt = 0; mt < 4; ++mt)
                #pragma unroll
                for (int nt = 0; nt < 2; ++nt)
                    acc[mt][nt] = MFMA_BF16(af[mt], bfv[nt], acc[mt][nt]);
        }
        cur ^= 1;
    }

    #pragma unroll
    for (int nt = 0; nt < 2; ++nt) {
        int col = n0 + wn * 32 + nt * 16 + l16;
        float bv = bias[col];
        #pragma unroll
        for (int mt = 0; mt < 4; ++mt) {
            int row = m0 + wm * 64 + mt * 16 + quad * 4;
            if (trans_out) {
                struct V4 { TC v[4]; } o;
                #pragma unroll
                for (int r = 0; r < 4; ++r)
                    o.v[r] = (TC)((acc[mt][nt][r] + bv) * scale);
                *(V4*)(&C[(size_t)col * M + row]) = o;
            } else {
                #pragma unroll
                for (int r = 0; r < 4; ++r)
                    C[(size_t)(row + r) * N + col] =
                        (TC)((acc[mt][nt][r] + bv) * scale);
            }
        }
    }
}

// ---------------- Q+K+V projections in one launch ---------------------------
// grid 640: [0,512) Q-proj (N=2048); [512,576) K-proj; [576,640) V-proj
// (transposed output VwT[dv][token]). All K=1024.
__global__ __launch_bounds__(512, 4) void proj_qkv(
    const bf16* __restrict__ aq, const bf16* __restrict__ ak,
    const bf16* __restrict__ av, const bf16* __restrict__ WqT,
    const bf16* __restrict__ WkT, const bf16* __restrict__ WvT,
    const float* __restrict__ bq, const float* __restrict__ bk,
    const float* __restrict__ bv, const float* __restrict__ qsc,
    bf16* __restrict__ Qw, bf16* __restrict__ Kw, bf16* __restrict__ VwT)
{
    __shared__ bf16 As[2][128 * 64];
    __shared__ bf16 Bs[2][128 * 64];
    int bid = blockIdx.x;
    if (bid < 512) {
        // scale = qsc / sqrt(128) * log2(e)  (exp2-domain softmax)
        float scale = qsc[0] * 0.08838834764831845f * 1.4426950408889634f;
        gemm_tile<bf16>(aq, WqT, bq, scale, Qw, 4096, 2048, 1024,
                        (bid >> 4) * 128, (bid & 15) * 128, false, As, Bs);
    } else if (bid < 576) {
        int b2 = bid - 512;
        gemm_tile<bf16>(ak, WkT, bk, 1.0f, Kw, 4096, 256, 1024,
                        (b2 >> 1) * 128, (b2 & 1) * 128, false, As, Bs);
    } else {
        int b2 = bid - 576;
        gemm_tile<bf16>(av, WvT, bv, 1.0f, VwT, 4096, 256, 1024,
                        (b2 >> 1) * 128, (b2 & 1) * 128, true, As, Bs);
    }
}

// ---------------- output projection -----------------------------------------
__global__ __launch_bounds__(512, 4) void proj_o(
    const bf16* __restrict__ Cw, const bf16* __restrict__ WoT,
    const float* __restrict__ bo, float* __restrict__ out)
{
    __shared__ bf16 As[2][128 * 64];
    __shared__ bf16 Bs[2][128 * 64];
    gemm_tile<float>(Cw, WoT, bo, 1.0f, out, 4096, 1024, 2048,
                     (blockIdx.x >> 3) * 128, (blockIdx.x & 7) * 128,
                     false, As, Bs);
}

// ---------------- flash attention (causal, GQA), 32x32 MFMA, pipelined ------
// grid (16,16,2); 256 thr = 4 waves = 2 q-subtiles(32 rows) x 2 kv-halves
// (32 keys). Paired passes: qt = 31-bx then bx (uniform 33 iters/block).
// LDS 64 KB flat: Kb0 [0,8K), Kb1 [8K,16K), Vb0 [16K,24K), Vb1 [24K,32K) bf16.
// T15 pipeline, ONE barrier/iter; K staged 1 tile ahead of V. iter t:
//   barrier (drains K(t+1)->Kb[(t+1)&1], V(t)->Vb[t&1])
//   stage K(t+2)->Kb[t&1], V(t+1)->Vb[(t+1)&1]   (targets' readers pre-barrier)
//   QK(t+1) -> sacc_next  [MFMA chain, independent of SM(t) -> overlap]
//   SM(t) on sacc_cur     [VALU fills QK's dep-stalls]
//   PV(t) from Vb[t&1]    [setprio(1) cluster]
// sacc rotation by unroll-2 with NAMED accumulators (rule #20).
__global__ __launch_bounds__(256, 2) void attn_fused(
    const bf16* __restrict__ Q,    // [B*L, H*128], pre-scaled
    const bf16* __restrict__ Kp,   // [B*L, G*128]
    const bf16* __restrict__ VT,   // [G*128, B*L]
    bf16* __restrict__ ctx)        // [B*L, H*128]
{
    __shared__ bf16 smem[32768];   // 64 KB

    const int tid  = threadIdx.x;
    const int wave = tid >> 6;
    const int lane = tid & 63;
    const int hi   = lane >> 5;
    const int l31  = lane & 31;
    const int s7   = l31 & 7;
    const int wq   = wave >> 1;    // q sub-tile (rows wq*32..+32 of block tile)
    const int kvw  = wave & 1;     // kv half (keys kvw*32..+32 of each kt tile)

    const int h = blockIdx.y;
    const int b = blockIdx.z;
    const int g = h >> 3;

    const bf16* kgbase = Kp + (size_t)(b * Lz) * (Gz * DQKz) + g * DQKz;
    const bf16* vgbase = VT + (size_t)(g * DVz) * (Bz * Lz) + b * Lz;

    // staging offsets (kt-invariant). LDS chunk ch of row r holds global
    // chunk ch^(r&7) (involution; read side applies the same XOR).
    int kgo[4], vgo[4], ldso[4];
    #pragma unroll
    for (int s = 0; s < 4; ++s) {
        int i = s * 256 + tid;
        ldso[s] = i * 8;
        int key = i >> 4, ck = (i & 15) ^ (key & 7);
        kgo[s] = key * (Gz * DQKz) + ck * 8;
        int dvr = i >> 3, cv = (i & 7) ^ (dvr & 7);
        vgo[s] = dvr * (Bz * Lz) + cv * 8;
    }
    auto stage_K = [&](int kt, int buf) {
        const bf16* kb = kgbase + (size_t)(kt * 64) * (Gz * DQKz);
        #pragma unroll
        for (int s = 0; s < 4; ++s)
            async_copy16(kb + kgo[s], smem + buf * 8192 + ldso[s]);
    };
    auto stage_V = [&](int kt, int buf) {
        const bf16* vb = vgbase + kt * 64;
        #pragma unroll
        for (int s = 0; s < 4; ++s)
            async_copy16(vb + vgo[s], smem + 16384 + buf * 8192 + ldso[s]);
    };

    // LDS read offsets (kt-invariant). K A-frag: row=kvw*32+l31, d-chunk
    // 2ks+hi; V A-frag: row=dt*32+l31, key-chunk kvw*4+kss*2+hi.
    int koff[8];
    #pragma unroll
    for (int ks = 0; ks < 8; ++ks)
        koff[ks] = ((kvw * 32 + l31) * 16 + ((ks * 2 + hi) ^ s7)) * 8;
    int voff[4][2];
    #pragma unroll
    for (int dt = 0; dt < 4; ++dt)
        #pragma unroll
        for (int kss = 0; kss < 2; ++kss)
            voff[dt][kss] = ((dt * 32 + l31) * 8
                             + ((kvw * 4 + kss * 2 + hi) ^ s7)) * 8;

    for (int pass = 0; pass < 2; ++pass) {
        const int qt  = pass == 0 ? (31 - (int)blockIdx.x) : (int)blockIdx.x;
        const int q0  = qt * 64;
        const int nkt = qt + 1;
        const int qrow = q0 + wq * 32 + l31;

        // Q fragments in registers: B-operand, qrow = lane col, 8 k-steps
        bf16x8 qf[8];
        {
            const bf16* qbase = Q + (size_t)(b * Lz + qrow) * (Hz * DQKz) + h * DQKz;
            #pragma unroll
            for (int s = 0; s < 8; ++s)
                qf[s] = *(const bf16x8*)(qbase + s * 16 + hi * 8);
        }

        // O^T dv-tiles: dv = dt*32 + crow, col = qrow. NAMED regs (rule #20).
        f32x16 oacc0 = {}, oacc1 = {}, oacc2 = {}, oacc3 = {};
        f32x16 saccA = {}, saccB = {};
        float lsum = 0.0f;

        if (pass) __syncthreads();   // protect epilogue-LDS reads of pass 0
        stage_K(0, 0);
        stage_V(0, 0);
        if (nkt > 1) stage_K(1, 1);
        __syncthreads();             // K(0), V(0), K(1) landed

        // QK(0) -> saccA
        {
            f32x16 s = {};
            #pragma unroll
            for (int ks = 0; ks < 8; ++ks) {
                bf16x8 kf = *(const bf16x8*)(smem + koff[ks]);
                s = MFMA32(kf, qf[ks], s);
            }
            saccA = s;
        }

        // pipelined iteration: scur = S(t); computes snxt = S(t+1).
        auto iter_body = [&](int t, f32x16& scur, f32x16& snxt) {
            __syncthreads();   // t=0: fences QK(0) readers of Kb0 before
                               // staging K(2); t>0: drains K(t+1), V(t).
            if (t + 2 < nkt) stage_K(t + 2, t & 1);
            if (t + 1 < nkt) stage_V(t + 1, (t + 1) & 1);

            // QK(t+1) -> snxt (independent of SM(t) below -> overlap)
            if (t + 1 < nkt) {
                const bf16* kc = smem + ((t + 1) & 1) * 8192;
                f32x16 s = {};
                #pragma unroll
                for (int ks = 0; ks < 8; ++ks) {
                    bf16x8 kf = *(const bf16x8*)(kc + koff[ks]);
                    s = MFMA32(kf, qf[ks], s);
                }
                snxt = s;
            }

            // SM(t): P = exp2(S - 8); mask only the diagonal tile.
            float pv[16];
            if (t == nkt - 1) {
                #pragma unroll
                for (int r = 0; r < 16; ++r) {
                    int key = kvw * 32 + (r & 3) + 8 * (r >> 2) + 4 * hi;
                    pv[r] = (key > wq * 32 + l31) ? 0.0f
                                                  : exp2f(scur[r] - 8.0f);
                }
            } else {
                #pragma unroll
                for (int r = 0; r < 16; ++r)
                    pv[r] = exp2f(scur[r] - 8.0f);
            }
            lsum += ((pv[0] + pv[1]) + (pv[2] + pv[3]))
                  + ((pv[4] + pv[5]) + (pv[6] + pv[7]))
                  + ((pv[8] + pv[9]) + (pv[10] + pv[11]))
                  + ((pv[12] + pv[13]) + (pv[14] + pv[15]));

            // P -> PV B-operand in registers (T12): pack pairs, swap halves.
            unsigned c0 = cvt_pk_bf16(pv[0],  pv[1]);
            unsigned c1 = cvt_pk_bf16(pv[2],  pv[3]);
            unsigned c2 = cvt_pk_bf16(pv[4],  pv[5]);
            unsigned c3 = cvt_pk_bf16(pv[6],  pv[7]);
            unsigned c4 = cvt_pk_bf16(pv[8],  pv[9]);
            unsigned c5 = cvt_pk_bf16(pv[10], pv[11]);
            unsigned c6 = cvt_pk_bf16(pv[12], pv[13]);
            unsigned c7 = cvt_pk_bf16(pv[14], pv[15]);
            asm("v_permlane32_swap_b32 %0, %1" : "+v"(c0), "+v"(c2));
            asm("v_permlane32_swap_b32 %0, %1" : "+v"(c1), "+v"(c3));
            asm("v_permlane32_swap_b32 %0, %1" : "+v"(c4), "+v"(c6));
            asm("v_permlane32_swap_b32 %0, %1" : "+v"(c5), "+v"(c7));
            union { unsigned u[4]; bf16x8 v; } p0 = {{c0, c1, c2, c3}};
            union { unsigned u[4]; bf16x8 v; } p1 = {{c4, c5, c6, c7}};

            // PV(t): O^T += V^T P^T : 4 dv-tiles x 2 k-steps
            const bf16* vcur = smem + 16384 + (t & 1) * 8192;
            __builtin_amdgcn_s_setprio(1);
            {
                bf16x8 vf;
                vf = *(const bf16x8*)(vcur + voff[0][0]); oacc0 = MFMA32(vf, p0.v, oacc0);
                vf = *(const bf16x8*)(vcur + voff[0][1]); oacc0 = MFMA32(vf, p1.v, oacc0);
                vf = *(const bf16x8*)(vcur + voff[1][0]); oacc1 = MFMA32(vf, p0.v, oacc1);
                vf = *(const bf16x8*)(vcur + voff[1][1]); oacc1 = MFMA32(vf, p1.v, oacc1);
                vf = *(const bf16x8*)(vcur + voff[2][0]); oacc2 = MFMA32(vf, p0.v, oacc2);
                vf = *(const bf16x8*)(vcur + voff[2][1]); oacc2 = MFMA32(vf, p1.v, oacc2);
                vf = *(const bf16x8*)(vcur + voff[3][0]); oacc3 = MFMA32(vf, p0.v, oacc3);
                vf = *(const bf16x8*)(vcur + voff[3][1]); oacc3 = MFMA32(vf, p1.v, oacc3);
            }
            __builtin_amdgcn_s_setprio(0);
        };

        int t = 0;
        for (; t + 2 <= nkt; t += 2) {
            iter_body(t,     saccA, saccB);
            iter_body(t + 1, saccB, saccA);
        }
        if (nkt & 1) iter_body(nkt - 1, saccA, saccB);

        // in-wave: combine hi halves (same qrow)
        lsum += __shfl_xor(lsum, 32);

        // cross-wave (kv-half) combine via LDS; stride 20 = conflict-free.
        // Flat over smem: E0 [0,5120), E1 [5120,10240), LS [10240,) floats.
        float* SM = (float*)smem;
        float* E0 = SM;
        float* E1 = SM + 5120;
        float* LS = SM + 10240;
        __syncthreads();                   // all waves done with K/V tiles

        auto store_partial = [&](f32x16 v, float* E) {
            #pragma unroll
            for (int j = 0; j < 4; ++j) {
                f32x4 v4 = { v[4 * j], v[4 * j + 1], v[4 * j + 2], v[4 * j + 3] };
                *(f32x4*)&E[(wave * 64 + lane) * 20 + 4 * j] = v4;
            }
        };
        if (kvw == 0) { store_partial(oacc2, E0); store_partial(oacc3, E1); }
        else          { store_partial(oacc0, E0); store_partial(oacc1, E1); }
        if (lane < 32) LS[wave * 32 + lane] = lsum;
        __syncthreads();
        lsum += LS[(wave ^ 1) * 32 + l31];
        const float inv = 1.0f / lsum;

        // finalize kept tiles: own partial + partner's, normalize, store.
        bf16* cbase = ctx + (size_t)(b * Lz + qrow) * (Hz * DVz) + h * DVz;
        auto finalize = [&](f32x16 v, float* E, int dt) {
            #pragma unroll
            for (int j = 0; j < 4; ++j) {
                f32x4 p4 = *(const f32x4*)&E[((wave ^ 1) * 64 + lane) * 20 + 4 * j];
                bf16x4 o4;
                #pragma unroll
                for (int r = 0; r < 4; ++r)
                    o4[r] = (bf16)((v[4 * j + r] + p4[r]) * inv);
                *(bf16x4*)&cbase[dt * 32 + j * 8 + hi * 4] = o4;
            }
        };
        if (kvw == 0) { finalize(oacc0, E0, 0); finalize(oacc1, E1, 1); }
        else          { finalize(oacc2, E0, 2); finalize(oacc3, E1, 3); }
    }
}

// ---------------------------------------------------------------------------
extern "C" void kernel_launch(void* const* d_in, const int* in_sizes, int n_in,
                              void* d_out, int out_size, void* d_ws, size_t ws_size,
                              hipStream_t stream)
{
    (void)in_sizes; (void)n_in; (void)out_size; (void)ws_size;

    const float* in_q = (const float*)d_in[0];
    const float* in_k = (const float*)d_in[1];
    const float* in_v = (const float*)d_in[2];
    const float* Wq   = (const float*)d_in[3];
    const float* bq   = (const float*)d_in[4];
    const float* Wk   = (const float*)d_in[5];
    const float* bk   = (const float*)d_in[6];
    const float* Wv   = (const float*)d_in[7];
    const float* bv   = (const float*)d_in[8];
    const float* Wo   = (const float*)d_in[9];
    const float* bo   = (const float*)d_in[10];
    const float* qsc  = (const float*)d_in[11];
    float* out = (float*)d_out;

    const int M = Bz * Lz;                       // 4096
    const int NQ = Hz * DQKz;                    // 2048
    const int NKV = Gz * DQKz;                   // 256

    // workspace (bf16 elems), ~53 MB; ak/av alias Cw (consumed before attn
    // writes ctx there).
    bf16* aq  = (bf16*)d_ws;                     // 4M
    bf16* WqT = aq  + (size_t)M * Dz;            // 2M
    bf16* WkT = WqT + (size_t)NQ * Dz;           // 0.25M
    bf16* WvT = WkT + (size_t)NKV * Dz;          // 0.25M
    bf16* WoT = WvT + (size_t)NKV * Dz;          // 2M
    bf16* Qw  = WoT + (size_t)Dz * NQ;           // 8M
    bf16* Kw  = Qw  + (size_t)M * NQ;            // 1M
    bf16* VwT = Kw  + (size_t)M * NKV;           // 1M
    bf16* Cw  = VwT + (size_t)NKV * M;           // 8M
    bf16* ak  = Cw;                              // alias (4M)
    bf16* av  = Cw + (size_t)M * Dz;             // alias (4M)

    // 1) prep: cvt + weight transposes
    prep<<<dim3(10752), dim3(256), 0, stream>>>(
        in_q, in_k, in_v, aq, ak, av, Wq, Wk, Wv, Wo, WqT, WkT, WvT, WoT);

    // 2) Q/K/V projections (one launch, 640 blocks)
    proj_qkv<<<dim3(640), dim3(512), 0, stream>>>(
        aq, ak, av, WqT, WkT, WvT, bq, bk, bv, qsc, Qw, Kw, VwT);

    // 3) attention (pair-balanced grid)
    attn_fused<<<dim3(16, Hz, Bz), dim3(256), 0, stream>>>(Qw, Kw, VwT, Cw);

    // 4) output projection -> fp32 out
    proj_o<<<dim3(256), dim3(512), 0, stream>>>(Cw, WoT, bo, out);
}

// Round 7
// 239.493 us; speedup vs baseline: 1.1761x; 1.0368x over previous
//
#include <hip/hip_runtime.h>

// ---------------------------------------------------------------------------
// Fused GQA attention: B=2, L=2048, D=1024, H=16, G=2, HPG=8, DQK=DV=128.
// Inputs fp32, OUTPUT fp32. bf16 MFMA compute, fp32 accumulation.
//
// Attention core on 32x32x16 MFMA with fully in-register P via
// v_cvt_pk_bf16_f32 + v_permlane32_swap_b32 (T12); T15 QK||SM pipeline
// (round-5 winner: 61.3us, MfmaUtil 24%). UNCHANGED this round.
//
// ROUND-6: proj_o retile 128x128 -> 64x128 (gemm_tile64). Old grid was 256
// blocks on 256 CUs = 1 block/CU (8 waves/CU, half of LDS-permitted
// residency) with a K=2048 loop. New: 512 blocks, LDS 48KB -> 2 blocks/CU
// resident = 16 waves/CU. Same staging/swizzle/fragment math.
// ---------------------------------------------------------------------------

typedef __bf16 bf16;
typedef __bf16 bf16x8 __attribute__((ext_vector_type(8)));
typedef __bf16 bf16x4 __attribute__((ext_vector_type(4)));
typedef float f32x4 __attribute__((ext_vector_type(4)));
typedef float f32x16 __attribute__((ext_vector_type(16)));
typedef float float4v __attribute__((ext_vector_type(4)));

#define MFMA_BF16(a, b, c) __builtin_amdgcn_mfma_f32_16x16x32_bf16((a), (b), (c), 0, 0, 0)
#define MFMA32(a, b, c)    __builtin_amdgcn_mfma_f32_32x32x16_bf16((a), (b), (c), 0, 0, 0)

static constexpr int Bz = 2, Lz = 2048, Dz = 1024;
static constexpr int Hz = 16, Gz = 2;
static constexpr int DQKz = 128, DVz = 128;

__device__ __forceinline__ void async_copy16(const bf16* g, bf16* l) {
    __builtin_amdgcn_global_load_lds(
        (const __attribute__((address_space(1))) unsigned int*)g,
        (__attribute__((address_space(3))) unsigned int*)l, 16, 0, 0);
}

__device__ __forceinline__ unsigned cvt_pk_bf16(float lo, float hi) {
    unsigned r;
    asm("v_cvt_pk_bf16_f32 %0, %1, %2" : "=v"(r) : "v"(lo), "v"(hi));
    return r;
}

// ---------------- prep: cvt q/k/v + all 4 weight transposes, one launch -----
// grid: 10752 blocks x 256 thr.
//   [0,6144): fp32->bf16 cvt of in_q/in_k/in_v (2048 blocks each, 2048 el/blk)
//   [6144,10752): 32x32 transpose tiles: Wq 2048, Wk 256, Wv 256, Wo 2048
__global__ __launch_bounds__(256) void prep(
    const float* __restrict__ q, const float* __restrict__ k,
    const float* __restrict__ v, bf16* __restrict__ dq,
    bf16* __restrict__ dk, bf16* __restrict__ dv,
    const float* __restrict__ Wq, const float* __restrict__ Wk,
    const float* __restrict__ Wv, const float* __restrict__ Wo,
    bf16* __restrict__ WqT, bf16* __restrict__ WkT,
    bf16* __restrict__ WvT, bf16* __restrict__ WoT)
{
    int bid = blockIdx.x;
    if (bid < 6144) {
        const float* s = bid < 2048 ? q : (bid < 4096 ? k : v);
        bf16* d = bid < 2048 ? dq : (bid < 4096 ? dk : dv);
        int i = (bid & 2047) * 2048 + threadIdx.x * 8;
        float4v a = *(const float4v*)(s + i);
        float4v b = *(const float4v*)(s + i + 4);
        bf16x8 o;
        #pragma unroll
        for (int j = 0; j < 4; ++j) { o[j] = (bf16)a[j]; o[j + 4] = (bf16)b[j]; }
        *(bf16x8*)(d + i) = o;
        return;
    }
    bid -= 6144;
    const float* W; bf16* WT; int K, N;
    if (bid < 2048)      { W = Wq; WT = WqT; K = 1024; N = 2048; }
    else if (bid < 2304) { W = Wk; WT = WkT; K = 1024; N = 256;  bid -= 2048; }
    else if (bid < 2560) { W = Wv; WT = WvT; K = 1024; N = 256;  bid -= 2304; }
    else                 { W = Wo; WT = WoT; K = 2048; N = 1024; bid -= 2560; }
    int tiles_n = N >> 5;
    int n0 = (bid % tiles_n) * 32, k0 = (bid / tiles_n) * 32;

    __shared__ bf16 t[32][33];
    int tx = threadIdx.x & 31, ty = threadIdx.x >> 5;
    #pragma unroll
    for (int i = 0; i < 4; ++i)
        t[ty + i * 8][tx] = (bf16)W[(size_t)(k0 + ty + i * 8) * N + n0 + tx];
    __syncthreads();
    #pragma unroll
    for (int i = 0; i < 4; ++i)
        WT[(size_t)(n0 + ty + i * 8) * K + k0 + tx] = t[tx][ty + i * 8];
}

// ---------------- pipelined GEMM body: 128x128 tile, BK64, 512 thr ----------
// 8 waves as 2(m) x 4(n); wave-tile 64x32. Double-buffered LDS, single
// barrier per k-iter, prefetch issued right after the barrier (attn-proven).
template <typename TC>
__device__ __forceinline__ void gemm_tile(
    const bf16* __restrict__ A, const bf16* __restrict__ BT,
    const float* __restrict__ bias, float scale, TC* __restrict__ C,
    int M, int N, int K, int m0, int n0, bool trans_out,
    bf16 (&As)[2][128 * 64], bf16 (&Bs)[2][128 * 64])
{
    const int tid  = threadIdx.x;        // 512
    const int wave = tid >> 6;
    const int lane = tid & 63;
    const int quad = lane >> 4;
    const int l16  = lane & 15;
    const int sw   = l16 & 7;
    const int wm = wave >> 2, wn = wave & 3;

    f32x4 acc[4][2] = {};

    auto stage = [&](int k0, int buf) {
        #pragma unroll
        for (int s = 0; s < 2; ++s) {
            int i = s * 512 + tid;
            int row = i >> 3, c = (i & 7) ^ (row & 7);
            async_copy16(A + (size_t)(m0 + row) * K + k0 + c * 8, &As[buf][i * 8]);
        }
        #pragma unroll
        for (int s = 0; s < 2; ++s) {
            int i = s * 512 + tid;
            int row = i >> 3, c = (i & 7) ^ (row & 7);
            async_copy16(BT + (size_t)(n0 + row) * K + k0 + c * 8, &Bs[buf][i * 8]);
        }
    };

    stage(0, 0);
    int cur = 0;
    for (int k0 = 0; k0 < K; k0 += 64) {
        __syncthreads();                    // drains loads issued last iter
        if (k0 + 64 < K) stage(k0 + 64, cur ^ 1);

        #pragma unroll
        for (int ks = 0; ks < 2; ++ks) {
            bf16x8 af[4], bfv[2];
            #pragma unroll
            for (int mt = 0; mt < 4; ++mt)
                af[mt] = *(const bf16x8*)(&As[cur][((wm * 64 + mt * 16 + l16) * 8
                                                    + ((ks * 4 + quad) ^ sw)) * 8]);
            #pragma unroll
            for (int nt = 0; nt < 2; ++nt)
                bfv[nt] = *(const bf16x8*)(&Bs[cur][((wn * 32 + nt * 16 + l16) * 8
                                                     + ((ks * 4 + quad) ^ sw)) * 8]);
            #pragma unroll
            for (int mt = 0; mt < 4; ++mt)
                #pragma unroll
                for (int nt = 0; nt < 2; ++nt)
                    acc[mt][nt] = MFMA_BF16(af[mt], bfv[nt], acc[mt][nt]);
        }
        cur ^= 1;
    }

    #pragma unroll
    for (int nt = 0; nt < 2; ++nt) {
        int col = n0 + wn * 32 + nt * 16 + l16;
        float bv = bias[col];
        #pragma unroll
        for (int mt = 0; mt < 4; ++mt) {
            int row = m0 + wm * 64 + mt * 16 + quad * 4;
            if (trans_out) {
                struct V4 { TC v[4]; } o;
                #pragma unroll
                for (int r = 0; r < 4; ++r)
                    o.v[r] = (TC)((acc[mt][nt][r] + bv) * scale);
                *(V4*)(&C[(size_t)col * M + row]) = o;
            } else {
                #pragma unroll
                for (int r = 0; r < 4; ++r)
                    C[(size_t)(row + r) * N + col] =
                        (TC)((acc[mt][nt][r] + bv) * scale);
            }
        }
    }
}

// ---------------- GEMM body 64x128 tile, BK64, 512 thr (proj_o) -------------
// 8 waves as 2(m) x 4(n); wave-tile 32x32 (acc[2][2]). LDS 48 KB ->
// 2 blocks/CU resident at grid 512 -> 16 waves/CU (vs 8 for the old
// 128x128/256-block config). Same staging swizzle + fragment math.
__device__ __forceinline__ void gemm_tile64(
    const bf16* __restrict__ A, const bf16* __restrict__ BT,
    const float* __restrict__ bias, float* __restrict__ C,
    int M, int N, int K, int m0, int n0,
    bf16 (&As)[2][64 * 64], bf16 (&Bs)[2][128 * 64])
{
    const int tid  = threadIdx.x;        // 512
    const int wave = tid >> 6;
    const int lane = tid & 63;
    const int quad = lane >> 4;
    const int l16  = lane & 15;
    const int sw   = l16 & 7;
    const int wm = wave >> 2, wn = wave & 3;   // 2m x 4n

    f32x4 acc[2][2] = {};

    auto stage = [&](int k0, int buf) {
        {
            int i = tid;                       // 64x64 = 512 x 16B, 1 round
            int row = i >> 3, c = (i & 7) ^ (row & 7);
            async_copy16(A + (size_t)(m0 + row) * K + k0 + c * 8, &As[buf][i * 8]);
        }
        #pragma unroll
        for (int s = 0; s < 2; ++s) {          // 128x64 = 2 rounds
            int i = s * 512 + tid;
            int row = i >> 3, c = (i & 7) ^ (row & 7);
            async_copy16(BT + (size_t)(n0 + row) * K + k0 + c * 8, &Bs[buf][i * 8]);
        }
    };

    stage(0, 0);
    int cur = 0;
    for (int k0 = 0; k0 < K; k0 += 64) {
        __syncthreads();                    // drains loads issued last iter
        if (k0 + 64 < K) stage(k0 + 64, cur ^ 1);

        #pragma unroll
        for (int ks = 0; ks < 2; ++ks) {
            bf16x8 af[2], bfv[2];
            #pragma unroll
            for (int mt = 0; mt < 2; ++mt)
                af[mt] = *(const bf16x8*)(&As[cur][((wm * 32 + mt * 16 + l16) * 8
                                                    + ((ks * 4 + quad) ^ sw)) * 8]);
            #pragma unroll
            for (int nt = 0; nt < 2; ++nt)
                bfv[nt] = *(const bf16x8*)(&Bs[cur][((wn * 32 + nt * 16 + l16) * 8
                                                     + ((ks * 4 + quad) ^ sw)) * 8]);
            #pragma unroll
            for (int mt = 0; mt < 2; ++mt)
                #pragma unroll
                for (int nt = 0; nt < 2; ++nt)
                    acc[mt][nt] = MFMA_BF16(af[mt], bfv[nt], acc[mt][nt]);
        }
        cur ^= 1;
    }

    #pragma unroll
    for (int nt = 0; nt < 2; ++nt) {
        int col = n0 + wn * 32 + nt * 16 + l16;
        float bv = bias[col];
        #pragma unroll
        for (int mt = 0; mt < 2; ++mt) {
            int row = m0 + wm * 32 + mt * 16 + quad * 4;
            #pragma unroll
            for (int r = 0; r < 4; ++r)
                C[(size_t)(row + r) * N + col] = acc[mt][nt][r] + bv;
        }
    }
}

// ---------------- Q+K+V projections in one launch ---------------------------
// grid 640: [0,512) Q-proj (N=2048); [512,576) K-proj; [576,640) V-proj
// (transposed output VwT[dv][token]). All K=1024.
__global__ __launch_bounds__(512, 4) void proj_qkv(
    const bf16* __restrict__ aq, const bf16* __restrict__ ak,
    const bf16* __restrict__ av, const bf16* __restrict__ WqT,
    const bf16* __restrict__ WkT, const bf16* __restrict__ WvT,
    const float* __restrict__ bq, const float* __restrict__ bk,
    const float* __restrict__ bv, const float* __restrict__ qsc,
    bf16* __restrict__ Qw, bf16* __restrict__ Kw, bf16* __restrict__ VwT)
{
    __shared__ bf16 As[2][128 * 64];
    __shared__ bf16 Bs[2][128 * 64];
    int bid = blockIdx.x;
    if (bid < 512) {
        // scale = qsc / sqrt(128) * log2(e)  (exp2-domain softmax)
        float scale = qsc[0] * 0.08838834764831845f * 1.4426950408889634f;
        gemm_tile<bf16>(aq, WqT, bq, scale, Qw, 4096, 2048, 1024,
                        (bid >> 4) * 128, (bid & 15) * 128, false, As, Bs);
    } else if (bid < 576) {
        int b2 = bid - 512;
        gemm_tile<bf16>(ak, WkT, bk, 1.0f, Kw, 4096, 256, 1024,
                        (b2 >> 1) * 128, (b2 & 1) * 128, false, As, Bs);
    } else {
        int b2 = bid - 576;
        gemm_tile<bf16>(av, WvT, bv, 1.0f, VwT, 4096, 256, 1024,
                        (b2 >> 1) * 128, (b2 & 1) * 128, true, As, Bs);
    }
}

// ---------------- output projection (64x128 tiles, 512 blocks) --------------
__global__ __launch_bounds__(512, 4) void proj_o(
    const bf16* __restrict__ Cw, const bf16* __restrict__ WoT,
    const float* __restrict__ bo, float* __restrict__ out)
{
    __shared__ bf16 As[2][64 * 64];
    __shared__ bf16 Bs[2][128 * 64];
    gemm_tile64(Cw, WoT, bo, out, 4096, 1024, 2048,
                (blockIdx.x >> 3) * 64, (blockIdx.x & 7) * 128, As, Bs);
}

// ---------------- flash attention (causal, GQA), 32x32 MFMA, pipelined ------
// grid (16,16,2); 256 thr = 4 waves = 2 q-subtiles(32 rows) x 2 kv-halves
// (32 keys). Paired passes: qt = 31-bx then bx (uniform 33 iters/block).
// LDS 64 KB flat: Kb0 [0,8K), Kb1 [8K,16K), Vb0 [16K,24K), Vb1 [24K,32K) bf16.
// T15 pipeline, ONE barrier/iter; K staged 1 tile ahead of V. iter t:
//   barrier (drains K(t+1)->Kb[(t+1)&1], V(t)->Vb[t&1])
//   stage K(t+2)->Kb[t&1], V(t+1)->Vb[(t+1)&1]   (targets' readers pre-barrier)
//   QK(t+1) -> sacc_next  [MFMA chain, independent of SM(t) -> overlap]
//   SM(t) on sacc_cur     [VALU fills QK's dep-stalls]
//   PV(t) from Vb[t&1]    [setprio(1) cluster]
// sacc rotation by unroll-2 with NAMED accumulators (rule #20).
__global__ __launch_bounds__(256, 2) void attn_fused(
    const bf16* __restrict__ Q,    // [B*L, H*128], pre-scaled
    const bf16* __restrict__ Kp,   // [B*L, G*128]
    const bf16* __restrict__ VT,   // [G*128, B*L]
    bf16* __restrict__ ctx)        // [B*L, H*128]
{
    __shared__ bf16 smem[32768];   // 64 KB

    const int tid  = threadIdx.x;
    const int wave = tid >> 6;
    const int lane = tid & 63;
    const int hi   = lane >> 5;
    const int l31  = lane & 31;
    const int s7   = l31 & 7;
    const int wq   = wave >> 1;    // q sub-tile (rows wq*32..+32 of block tile)
    const int kvw  = wave & 1;     // kv half (keys kvw*32..+32 of each kt tile)

    const int h = blockIdx.y;
    const int b = blockIdx.z;
    const int g = h >> 3;

    const bf16* kgbase = Kp + (size_t)(b * Lz) * (Gz * DQKz) + g * DQKz;
    const bf16* vgbase = VT + (size_t)(g * DVz) * (Bz * Lz) + b * Lz;

    // staging offsets (kt-invariant). LDS chunk ch of row r holds global
    // chunk ch^(r&7) (involution; read side applies the same XOR).
    int kgo[4], vgo[4], ldso[4];
    #pragma unroll
    for (int s = 0; s < 4; ++s) {
        int i = s * 256 + tid;
        ldso[s] = i * 8;
        int key = i >> 4, ck = (i & 15) ^ (key & 7);
        kgo[s] = key * (Gz * DQKz) + ck * 8;
        int dvr = i >> 3, cv = (i & 7) ^ (dvr & 7);
        vgo[s] = dvr * (Bz * Lz) + cv * 8;
    }
    auto stage_K = [&](int kt, int buf) {
        const bf16* kb = kgbase + (size_t)(kt * 64) * (Gz * DQKz);
        #pragma unroll
        for (int s = 0; s < 4; ++s)
            async_copy16(kb + kgo[s], smem + buf * 8192 + ldso[s]);
    };
    auto stage_V = [&](int kt, int buf) {
        const bf16* vb = vgbase + kt * 64;
        #pragma unroll
        for (int s = 0; s < 4; ++s)
            async_copy16(vb + vgo[s], smem + 16384 + buf * 8192 + ldso[s]);
    };

    // LDS read offsets (kt-invariant). K A-frag: row=kvw*32+l31, d-chunk
    // 2ks+hi; V A-frag: row=dt*32+l31, key-chunk kvw*4+kss*2+hi.
    int koff[8];
    #pragma unroll
    for (int ks = 0; ks < 8; ++ks)
        koff[ks] = ((kvw * 32 + l31) * 16 + ((ks * 2 + hi) ^ s7)) * 8;
    int voff[4][2];
    #pragma unroll
    for (int dt = 0; dt < 4; ++dt)
        #pragma unroll
        for (int kss = 0; kss < 2; ++kss)
            voff[dt][kss] = ((dt * 32 + l31) * 8
                             + ((kvw * 4 + kss * 2 + hi) ^ s7)) * 8;

    for (int pass = 0; pass < 2; ++pass) {
        const int qt  = pass == 0 ? (31 - (int)blockIdx.x) : (int)blockIdx.x;
        const int q0  = qt * 64;
        const int nkt = qt + 1;
        const int qrow = q0 + wq * 32 + l31;

        // Q fragments in registers: B-operand, qrow = lane col, 8 k-steps
        bf16x8 qf[8];
        {
            const bf16* qbase = Q + (size_t)(b * Lz + qrow) * (Hz * DQKz) + h * DQKz;
            #pragma unroll
            for (int s = 0; s < 8; ++s)
                qf[s] = *(const bf16x8*)(qbase + s * 16 + hi * 8);
        }

        // O^T dv-tiles: dv = dt*32 + crow, col = qrow. NAMED regs (rule #20).
        f32x16 oacc0 = {}, oacc1 = {}, oacc2 = {}, oacc3 = {};
        f32x16 saccA = {}, saccB = {};
        float lsum = 0.0f;

        if (pass) __syncthreads();   // protect epilogue-LDS reads of pass 0
        stage_K(0, 0);
        stage_V(0, 0);
        if (nkt > 1) stage_K(1, 1);
        __syncthreads();             // K(0), V(0), K(1) landed

        // QK(0) -> saccA
        {
            f32x16 s = {};
            #pragma unroll
            for (int ks = 0; ks < 8; ++ks) {
                bf16x8 kf = *(const bf16x8*)(smem + koff[ks]);
                s = MFMA32(kf, qf[ks], s);
            }
            saccA = s;
        }

        // pipelined iteration: scur = S(t); computes snxt = S(t+1).
        auto iter_body = [&](int t, f32x16& scur, f32x16& snxt) {
            __syncthreads();   // t=0: fences QK(0) readers of Kb0 before
                               // staging K(2); t>0: drains K(t+1), V(t).
            if (t + 2 < nkt) stage_K(t + 2, t & 1);
            if (t + 1 < nkt) stage_V(t + 1, (t + 1) & 1);

            // QK(t+1) -> snxt (independent of SM(t) below -> overlap)
            if (t + 1 < nkt) {
                const bf16* kc = smem + ((t + 1) & 1) * 8192;
                f32x16 s = {};
                #pragma unroll
                for (int ks = 0; ks < 8; ++ks) {
                    bf16x8 kf = *(const bf16x8*)(kc + koff[ks]);
                    s = MFMA32(kf, qf[ks], s);
                }
                snxt = s;
            }

            // SM(t): P = exp2(S - 8); mask only the diagonal tile.
            float pv[16];
            if (t == nkt - 1) {
                #pragma unroll
                for (int r = 0; r < 16; ++r) {
                    int key = kvw * 32 + (r & 3) + 8 * (r >> 2) + 4 * hi;
                    pv[r] = (key > wq * 32 + l31) ? 0.0f
                                                  : exp2f(scur[r] - 8.0f);
                }
            } else {
                #pragma unroll
                for (int r = 0; r < 16; ++r)
                    pv[r] = exp2f(scur[r] - 8.0f);
            }
            lsum += ((pv[0] + pv[1]) + (pv[2] + pv[3]))
                  + ((pv[4] + pv[5]) + (pv[6] + pv[7]))
                  + ((pv[8] + pv[9]) + (pv[10] + pv[11]))
                  + ((pv[12] + pv[13]) + (pv[14] + pv[15]));

            // P -> PV B-operand in registers (T12): pack pairs, swap halves.
            unsigned c0 = cvt_pk_bf16(pv[0],  pv[1]);
            unsigned c1 = cvt_pk_bf16(pv[2],  pv[3]);
            unsigned c2 = cvt_pk_bf16(pv[4],  pv[5]);
            unsigned c3 = cvt_pk_bf16(pv[6],  pv[7]);
            unsigned c4 = cvt_pk_bf16(pv[8],  pv[9]);
            unsigned c5 = cvt_pk_bf16(pv[10], pv[11]);
            unsigned c6 = cvt_pk_bf16(pv[12], pv[13]);
            unsigned c7 = cvt_pk_bf16(pv[14], pv[15]);
            asm("v_permlane32_swap_b32 %0, %1" : "+v"(c0), "+v"(c2));
            asm("v_permlane32_swap_b32 %0, %1" : "+v"(c1), "+v"(c3));
            asm("v_permlane32_swap_b32 %0, %1" : "+v"(c4), "+v"(c6));
            asm("v_permlane32_swap_b32 %0, %1" : "+v"(c5), "+v"(c7));
            union { unsigned u[4]; bf16x8 v; } p0 = {{c0, c1, c2, c3}};
            union { unsigned u[4]; bf16x8 v; } p1 = {{c4, c5, c6, c7}};

            // PV(t): O^T += V^T P^T : 4 dv-tiles x 2 k-steps
            const bf16* vcur = smem + 16384 + (t & 1) * 8192;
            __builtin_amdgcn_s_setprio(1);
            {
                bf16x8 vf;
                vf = *(const bf16x8*)(vcur + voff[0][0]); oacc0 = MFMA32(vf, p0.v, oacc0);
                vf = *(const bf16x8*)(vcur + voff[0][1]); oacc0 = MFMA32(vf, p1.v, oacc0);
                vf = *(const bf16x8*)(vcur + voff[1][0]); oacc1 = MFMA32(vf, p0.v, oacc1);
                vf = *(const bf16x8*)(vcur + voff[1][1]); oacc1 = MFMA32(vf, p1.v, oacc1);
                vf = *(const bf16x8*)(vcur + voff[2][0]); oacc2 = MFMA32(vf, p0.v, oacc2);
                vf = *(const bf16x8*)(vcur + voff[2][1]); oacc2 = MFMA32(vf, p1.v, oacc2);
                vf = *(const bf16x8*)(vcur + voff[3][0]); oacc3 = MFMA32(vf, p0.v, oacc3);
                vf = *(const bf16x8*)(vcur + voff[3][1]); oacc3 = MFMA32(vf, p1.v, oacc3);
            }
            __builtin_amdgcn_s_setprio(0);
        };

        int t = 0;
        for (; t + 2 <= nkt; t += 2) {
            iter_body(t,     saccA, saccB);
            iter_body(t + 1, saccB, saccA);
        }
        if (nkt & 1) iter_body(nkt - 1, saccA, saccB);

        // in-wave: combine hi halves (same qrow)
        lsum += __shfl_xor(lsum, 32);

        // cross-wave (kv-half) combine via LDS; stride 20 = conflict-free.
        // Flat over smem: E0 [0,5120), E1 [5120,10240), LS [10240,) floats.
        float* SM = (float*)smem;
        float* E0 = SM;
        float* E1 = SM + 5120;
        float* LS = SM + 10240;
        __syncthreads();                   // all waves done with K/V tiles

        auto store_partial = [&](f32x16 v, float* E) {
            #pragma unroll
            for (int j = 0; j < 4; ++j) {
                f32x4 v4 = { v[4 * j], v[4 * j + 1], v[4 * j + 2], v[4 * j + 3] };
                *(f32x4*)&E[(wave * 64 + lane) * 20 + 4 * j] = v4;
            }
        };
        if (kvw == 0) { store_partial(oacc2, E0); store_partial(oacc3, E1); }
        else          { store_partial(oacc0, E0); store_partial(oacc1, E1); }
        if (lane < 32) LS[wave * 32 + lane] = lsum;
        __syncthreads();
        lsum += LS[(wave ^ 1) * 32 + l31];
        const float inv = 1.0f / lsum;

        // finalize kept tiles: own partial + partner's, normalize, store.
        bf16* cbase = ctx + (size_t)(b * Lz + qrow) * (Hz * DVz) + h * DVz;
        auto finalize = [&](f32x16 v, float* E, int dt) {
            #pragma unroll
            for (int j = 0; j < 4; ++j) {
                f32x4 p4 = *(const f32x4*)&E[((wave ^ 1) * 64 + lane) * 20 + 4 * j];
                bf16x4 o4;
                #pragma unroll
                for (int r = 0; r < 4; ++r)
                    o4[r] = (bf16)((v[4 * j + r] + p4[r]) * inv);
                *(bf16x4*)&cbase[dt * 32 + j * 8 + hi * 4] = o4;
            }
        };
        if (kvw == 0) { finalize(oacc0, E0, 0); finalize(oacc1, E1, 1); }
        else          { finalize(oacc2, E0, 2); finalize(oacc3, E1, 3); }
    }
}

// ---------------------------------------------------------------------------
extern "C" void kernel_launch(void* const* d_in, const int* in_sizes, int n_in,
                              void* d_out, int out_size, void* d_ws, size_t ws_size,
                              hipStream_t stream)
{
    (void)in_sizes; (void)n_in; (void)out_size; (void)ws_size;

    const float* in_q = (const float*)d_in[0];
    const float* in_k = (const float*)d_in[1];
    const float* in_v = (const float*)d_in[2];
    const float* Wq   = (const float*)d_in[3];
    const float* bq   = (const float*)d_in[4];
    const float* Wk   = (const float*)d_in[5];
    const float* bk   = (const float*)d_in[6];
    const float* Wv   = (const float*)d_in[7];
    const float* bv   = (const float*)d_in[8];
    const float* Wo   = (const float*)d_in[9];
    const float* bo   = (const float*)d_in[10];
    const float* qsc  = (const float*)d_in[11];
    float* out = (float*)d_out;

    const int M = Bz * Lz;                       // 4096
    const int NQ = Hz * DQKz;                    // 2048
    const int NKV = Gz * DQKz;                   // 256

    // workspace (bf16 elems), ~53 MB; ak/av alias Cw (consumed before attn
    // writes ctx there).
    bf16* aq  = (bf16*)d_ws;                     // 4M
    bf16* WqT = aq  + (size_t)M * Dz;            // 2M
    bf16* WkT = WqT + (size_t)NQ * Dz;           // 0.25M
    bf16* WvT = WkT + (size_t)NKV * Dz;          // 0.25M
    bf16* WoT = WvT + (size_t)NKV * Dz;          // 2M
    bf16* Qw  = WoT + (size_t)Dz * NQ;           // 8M
    bf16* Kw  = Qw  + (size_t)M * NQ;            // 1M
    bf16* VwT = Kw  + (size_t)M * NKV;           // 1M
    bf16* Cw  = VwT + (size_t)NKV * M;           // 8M
    bf16* ak  = Cw;                              // alias (4M)
    bf16* av  = Cw + (size_t)M * Dz;             // alias (4M)

    // 1) prep: cvt + weight transposes
    prep<<<dim3(10752), dim3(256), 0, stream>>>(
        in_q, in_k, in_v, aq, ak, av, Wq, Wk, Wv, Wo, WqT, WkT, WvT, WoT);

    // 2) Q/K/V projections (one launch, 640 blocks)
    proj_qkv<<<dim3(640), dim3(512), 0, stream>>>(
        aq, ak, av, WqT, WkT, WvT, bq, bk, bv, qsc, Qw, Kw, VwT);

    // 3) attention (pair-balanced grid)
    attn_fused<<<dim3(16, Hz, Bz), dim3(256), 0, stream>>>(Qw, Kw, VwT, Cw);

    // 4) output projection -> fp32 out (64x128 tiles, 512 blocks)
    proj_o<<<dim3(512), dim3(512), 0, stream>>>(Cw, WoT, bo, out);
}